// Round 14
// baseline (181.637 us; speedup 1.0000x reference)
//
#include <hip/hip_runtime.h>

// PostProcessor3D: threshold(>0.9) + 5x5x5 stride-1 maxpool + strict-local-max
// mask on [64,512,512] fp32.
//
// R14 = R13 resubmitted verbatim (R13 hit a GPU-acquisition timeout; never ran).
//
// R13: maximize concurrent slice-chains per CU. R12 was correct but ran only
// 4 blocks/CU (grid-limited) at 21% occupancy -- the serial per-slice chain
// has nothing to overlap with. Changes:
//   - 320-thread blocks (20 rows x 16 cols): every thread stages exactly ONE
//     wm quad (3 overlapping global b128 loads -> register 5-tap W-max ->
//     one LDS write). No second-quad path, prefetch regs halved (12 VGPRs).
//   - __launch_bounds__(320, 8) -> target VGPR<=64 -> 32-wave/CU tier ->
//     6 resident blocks/CU (LDS 19.6KB x 6 = 117KB).
//   - DCHUNK 16->8 -> grid 2048 = 8 assigned/CU keeps the 6 slots fed.
//   - grid (W,H,D): D-neighbor chunks 256 ids apart -> same XCD under %8
//     dispatch -> D-halo re-reads are L2-local.
// Kept (proven R11/R12): raw-max trick (thresh commutes with max; center in
// own window => out = (c>0.9 && c==rawmax)?c:0; zero-pad == -inf pad), one
// no-drain barrier/slice (lgkmcnt only; prefetch loads fly across), dbuf
// wm/cen, dist-1 register prefetch, fully-unrolled loop (constant ring
// indices; no scratch spill -- R3 lesson).
//
// Hazards (1 barrier + dbuf): wm/cen write@stage(t) -> read@consume(t): B(t).
// read@consume(t) -> rewrite@stage(t+2): B(t+1) between. OK.
// Waves 0-3 stage rows 0..15 + consume; wave 4 stages rows 16..19 only
// (wave-uniform branch).

#define THRESH 0.9f

constexpr int D = 64, H = 512, W = 512;
constexpr int HW = H * W;
constexpr int TW = 64;                    // tile width in floats (16 quads)
constexpr int TH = 16;                    // tile height (output rows)
constexpr int DCHUNK = 8;                 // depth outputs per block
constexpr int HALO = 2;
constexpr int LROWS = TH + 2 * HALO;      // 20 staged rows
constexpr int WM_S = 17;                  // wm row stride (16 quads + pad)
constexpr int CEN_S = 17;                 // cen row stride
constexpr int NS = DCHUNK + 2 * HALO;     // 12 slices per block

typedef float floatx4 __attribute__((ext_vector_type(4)));

__device__ __forceinline__ void barrier_no_drain() {
    asm volatile("s_waitcnt lgkmcnt(0)\n\ts_barrier" ::: "memory");
}

__device__ __forceinline__ float4 max4(float4 a, float4 b) {
    return make_float4(fmaxf(a.x, b.x), fmaxf(a.y, b.y),
                       fmaxf(a.z, b.z), fmaxf(a.w, b.w));
}

// 5-tap sliding max for middle quad b given (left a, mid b, right c).
// f0 = a.x; out[j] = max(f[2+j .. 6+j]).
__device__ __forceinline__ float4 wmax5(float4 a, float4 b, float4 c) {
    const float f2 = a.z, f3 = a.w, f4 = b.x, f5 = b.y, f6 = b.z, f7 = b.w;
    const float f8 = c.x, f9 = c.y;
    const float m45 = fmaxf(f4, f5);
    const float m56 = fmaxf(f5, f6);
    const float m345 = fmaxf(f3, m45);
    const float m456 = fmaxf(f4, m56);
    const float m567 = fmaxf(m56, f7);
    const float m678 = fmaxf(fmaxf(f6, f7), f8);
    float4 r;
    r.x = fmaxf(fmaxf(f2, f6), m345);
    r.y = fmaxf(fmaxf(f3, f7), m456);
    r.z = fmaxf(fmaxf(f4, f8), m567);
    r.w = fmaxf(fmaxf(f5, f9), m678);
    return r;
}

__global__ __launch_bounds__(320, 8)
void peak3d_kernel(const float* __restrict__ in, float* __restrict__ out) {
    __shared__ float4 wm [2][LROWS * WM_S];   // W-maxed quads: 2x340 = 10880 B
    __shared__ float4 cen[2][TH * CEN_S];     // raw center quads: 2x272 = 8704 B

    const int tx = threadIdx.x;               // 0..15: quad col
    const int ty = threadIdx.y;               // 0..19: staged row

    const int w0 = blockIdx.x * TW;
    const int h0 = blockIdx.y * TH;
    const int d0 = blockIdx.z * DCHUNK;

    // One staged wm quad per thread: row ty, output-quad col tx.
    const int gh  = h0 + ty - HALO;
    const bool vR = (unsigned)gh < (unsigned)H;
    const int gwl = w0 + 4 * tx - 4;          // left neighbor quad
    const int gwm = w0 + 4 * tx;              // own quad (always in-bounds)
    const int gwr = w0 + 4 * tx + 4;          // right neighbor quad
    const bool vl = vR && (gwl >= 0);
    const bool vr = vR && (gwr < W);
    const size_t rbase = (size_t)(vR ? gh : 0) * W;
    const size_t offl = rbase + (gwl >= 0 ? gwl : 0);
    const size_t offm = rbase + gwm;
    const size_t offr = rbase + (gwr < W ? gwr : 0);

    const float4 zero4 = make_float4(0.f, 0.f, 0.f, 0.f);
    float4 win[5], cen_r[3];
#pragma unroll
    for (int k = 0; k < 5; ++k) win[k] = zero4;
#pragma unroll
    for (int k = 0; k < 3; ++k) cen_r[k] = zero4;

    auto ld4 = [&](size_t off) {
        return *reinterpret_cast<const float4*>(in + off);
    };
    auto loadStage = [&](int dd, float4* pf) {
        pf[0] = zero4; pf[1] = zero4; pf[2] = zero4;
        if (dd >= 0 && dd < D) {              // wave-uniform
            const size_t sb = (size_t)dd * HW;
            if (vl) pf[0] = ld4(sb + offl);
            if (vR) pf[1] = ld4(sb + offm);
            if (vr) pf[2] = ld4(sb + offr);
        }
    };

    float4 pf[3];
    loadStage(d0 - HALO, pf);                 // prime slice 0

#pragma unroll
    for (int t = 0; t < NS; ++t) {            // fully unrolled: t constant
        const int buf = t & 1;

        // ---- stage: register W-max -> wm; raw center -> cen ----
        wm[buf][ty * WM_S + tx] = wmax5(pf[0], pf[1], pf[2]);
        if (ty >= HALO && ty < TH + HALO)     // staged rows 2..17 = centers
            cen[buf][(ty - HALO) * CEN_S + tx] = pf[1];

        // prefetch slice t+1 (in flight across barrier + consume)
        if (t + 1 < NS) loadStage(d0 - HALO + t + 1, pf);

        barrier_no_drain();                   // the only barrier per slice

        // ---- consume (waves 0-3 only): H-max + rings + output ----
        if (ty < TH) {                        // wave-uniform
            const float4* wp = &wm[buf][ty * WM_S + tx];
            const float4 hv = max4(max4(max4(wp[0 * WM_S], wp[1 * WM_S]),
                                        max4(wp[3 * WM_S], wp[4 * WM_S])),
                                   wp[2 * WM_S]);
            win[t % 5] = hv;                  // HW-max of slice t
            cen_r[t % 3] = cen[buf][ty * CEN_S + tx];

            if (t >= 4) {
                const int dout = d0 + (t - 4);     // window center slice t-2
                const float4 mp = max4(max4(max4(win[0], win[1]),
                                            max4(win[2], win[3])), win[4]);
                const float4 c = cen_r[(t + 1) % 3];  // written at iter t-2
                floatx4 res;
                res.x = (c.x > THRESH && mp.x == c.x) ? c.x : 0.f;
                res.y = (c.y > THRESH && mp.y == c.y) ? c.y : 0.f;
                res.z = (c.z > THRESH && mp.z == c.z) ? c.z : 0.f;
                res.w = (c.w > THRESH && mp.w == c.w) ? c.w : 0.f;
                floatx4* op = reinterpret_cast<floatx4*>(
                    out + (size_t)dout * HW + (size_t)(h0 + ty) * W +
                    (w0 + 4 * tx));
                __builtin_nontemporal_store(res, op);
            }
        }
    }
}

extern "C" void kernel_launch(void* const* d_in, const int* in_sizes, int n_in,
                              void* d_out, int out_size, void* d_ws, size_t ws_size,
                              hipStream_t stream) {
    const float* in = (const float*)d_in[0];
    float* out = (float*)d_out;
    dim3 grid(W / TW, H / TH, D / DCHUNK);    // 8 x 32 x 8 = 2048 blocks
    dim3 block(16, LROWS, 1);                 // 320 threads = 5 waves
    hipLaunchKernelGGL(peak3d_kernel, grid, block, 0, stream, in, out);
}

// Round 15
// 144.790 us; speedup vs baseline: 1.2545x; 1.2545x over previous
//
#include <hip/hip_runtime.h>

// PostProcessor3D: threshold(>0.9) + 5x5x5 stride-1 maxpool + strict-local-max
// mask on [64,512,512] fp32.
//
// R15: R13/R14's occupancy push was right (occupancy 21->55%) but the 64-VGPR
// cap spilled ~76 VGPRs of live state to scratch (VGPR=32, WRITE 2x, dur 2x).
// Keep the cap; shrink the state to fit:
//   - cen LDS array + cen_r[3] ring DELETED: the strict-max compare needs the
//     raw center in[dout,h,w] -- just re-load it from global during the stage
//     phase (issued pre-barrier, lands during barrier + H-max; staged 2
//     slices ago -> L1/L2 hit). One cen_pf register.
//   - 32-bit per-thread offsets (slice base is wave-uniform -> SGPR).
//   - LDS = dbuf wm only (10.9 KB) -> 6 resident blocks/CU at 65 KB.
// Live state: pf[3](12q) + win[5](20q) + cen_pf(4q) = 36 quad-regs + ~15
// scalar overhead ~= 55-60 VGPR < 64 cap -> 30 waves/CU, no spill.
//
// Kept (proven): 320-thread blocks (20 rows x 16 cols, 1 wm quad/thread,
// producer-side register W-max from 3 overlapping global b128 loads), raw-max
// trick (out = (c>0.9 && c==rawmax5^3) ? c : 0; zero-pad == -inf pad), one
// no-drain barrier/slice (lgkmcnt only), dist-1 slice prefetch, fully
// unrolled loop (constant ring indices).
//
// Hazards (1 barrier + dbuf wm): write@stage(t) -> B(t) -> read@consume(t);
// read@consume(t) -> B(t+1) -> rewrite@stage(t+2). OK.

#define THRESH 0.9f

constexpr int D = 64, H = 512, W = 512;
constexpr int HW = H * W;
constexpr int TW = 64;                    // tile width in floats (16 quads)
constexpr int TH = 16;                    // tile height (output rows)
constexpr int DCHUNK = 8;                 // depth outputs per block
constexpr int HALO = 2;
constexpr int LROWS = TH + 2 * HALO;      // 20 staged rows
constexpr int WM_S = 17;                  // wm row stride (16 quads + pad)
constexpr int NS = DCHUNK + 2 * HALO;     // 12 slices per block

typedef float floatx4 __attribute__((ext_vector_type(4)));

__device__ __forceinline__ void barrier_no_drain() {
    asm volatile("s_waitcnt lgkmcnt(0)\n\ts_barrier" ::: "memory");
}

__device__ __forceinline__ float4 max4(float4 a, float4 b) {
    return make_float4(fmaxf(a.x, b.x), fmaxf(a.y, b.y),
                       fmaxf(a.z, b.z), fmaxf(a.w, b.w));
}

// 5-tap sliding max for middle quad b given (left a, mid b, right c).
__device__ __forceinline__ float4 wmax5(float4 a, float4 b, float4 c) {
    const float f2 = a.z, f3 = a.w, f4 = b.x, f5 = b.y, f6 = b.z, f7 = b.w;
    const float f8 = c.x, f9 = c.y;
    const float m45 = fmaxf(f4, f5);
    const float m56 = fmaxf(f5, f6);
    const float m345 = fmaxf(f3, m45);
    const float m456 = fmaxf(f4, m56);
    const float m567 = fmaxf(m56, f7);
    const float m678 = fmaxf(fmaxf(f6, f7), f8);
    float4 r;
    r.x = fmaxf(fmaxf(f2, f6), m345);
    r.y = fmaxf(fmaxf(f3, f7), m456);
    r.z = fmaxf(fmaxf(f4, f8), m567);
    r.w = fmaxf(fmaxf(f5, f9), m678);
    return r;
}

__global__ __launch_bounds__(320, 8)
void peak3d_kernel(const float* __restrict__ in, float* __restrict__ out) {
    __shared__ float4 wm[2][LROWS * WM_S];    // 2 x 340 quads = 10880 B

    const int tx = threadIdx.x;               // 0..15: quad col
    const int ty = threadIdx.y;               // 0..19: staged row

    const int w0 = blockIdx.x * TW;
    const int h0 = blockIdx.y * TH;
    const int d0 = blockIdx.z * DCHUNK;

    // One staged wm quad per thread: row ty, output-quad col tx.
    const int gh  = h0 + ty - HALO;
    const bool vR = (unsigned)gh < (unsigned)H;
    const int gwl = w0 + 4 * tx - 4;          // left neighbor quad
    const int gwr = w0 + 4 * tx + 4;          // right neighbor quad
    const bool vl = vR && (gwl >= 0);
    const bool vr = vR && (gwr < W);
    const unsigned rbase = (unsigned)(vR ? gh : 0) * W;
    const unsigned offl = rbase + (unsigned)(gwl >= 0 ? gwl : 0);
    const unsigned offm = rbase + (unsigned)(w0 + 4 * tx);
    const unsigned offr = rbase + (unsigned)(gwr < W ? gwr : 0);
    // center/output offset within a slice (only used when ty < TH)
    const unsigned ocen = (unsigned)(h0 + ty) * W + (unsigned)(w0 + 4 * tx);

    const float4 zero4 = make_float4(0.f, 0.f, 0.f, 0.f);
    float4 win[5];
#pragma unroll
    for (int k = 0; k < 5; ++k) win[k] = zero4;
    float4 cen_pf = zero4;

    auto ld4 = [](const float* sb, unsigned off) {
        return *reinterpret_cast<const float4*>(sb + off);
    };
    auto loadStage = [&](int dd, float4* pf) {
        pf[0] = zero4; pf[1] = zero4; pf[2] = zero4;
        if (dd >= 0 && dd < D) {              // wave-uniform
            const float* sb = in + (size_t)dd * HW;
            if (vl) pf[0] = ld4(sb, offl);
            if (vR) pf[1] = ld4(sb, offm);
            if (vr) pf[2] = ld4(sb, offr);
        }
    };

    float4 pf[3];
    loadStage(d0 - HALO, pf);                 // prime slice 0

#pragma unroll
    for (int t = 0; t < NS; ++t) {            // fully unrolled: t constant
        const int buf = t & 1;

        // ---- stage: register W-max -> wm ----
        wm[buf][ty * WM_S + tx] = wmax5(pf[0], pf[1], pf[2]);

        // center re-load for this iteration's output (L1/L2 hit: staged 2
        // slices ago); issued pre-barrier, consumed post-barrier.
        if (t >= 4 && ty < TH)                // wave-uniform
            cen_pf = ld4(in + (size_t)(d0 + (t - 4)) * HW, ocen);

        // prefetch slice t+1 (in flight across barrier + consume)
        if (t + 1 < NS) loadStage(d0 - HALO + t + 1, pf);

        barrier_no_drain();                   // the only barrier per slice

        // ---- consume (waves 0-3): H-max + D-ring + strict-max + store ----
        if (ty < TH) {                        // wave-uniform
            const float4* wp = &wm[buf][ty * WM_S + tx];
            const float4 hv = max4(max4(max4(wp[0 * WM_S], wp[1 * WM_S]),
                                        max4(wp[3 * WM_S], wp[4 * WM_S])),
                                   wp[2 * WM_S]);
            win[t % 5] = hv;                  // HW-max of slice t

            if (t >= 4) {
                const int dout = d0 + (t - 4);     // window center slice t-2
                const float4 mp = max4(max4(max4(win[0], win[1]),
                                            max4(win[2], win[3])), win[4]);
                const float4 c = cen_pf;
                floatx4 res;
                res.x = (c.x > THRESH && mp.x == c.x) ? c.x : 0.f;
                res.y = (c.y > THRESH && mp.y == c.y) ? c.y : 0.f;
                res.z = (c.z > THRESH && mp.z == c.z) ? c.z : 0.f;
                res.w = (c.w > THRESH && mp.w == c.w) ? c.w : 0.f;
                floatx4* op = reinterpret_cast<floatx4*>(
                    out + (size_t)dout * HW + ocen);
                __builtin_nontemporal_store(res, op);
            }
        }
    }
}

extern "C" void kernel_launch(void* const* d_in, const int* in_sizes, int n_in,
                              void* d_out, int out_size, void* d_ws, size_t ws_size,
                              hipStream_t stream) {
    const float* in = (const float*)d_in[0];
    float* out = (float*)d_out;
    dim3 grid(W / TW, H / TH, D / DCHUNK);    // 8 x 32 x 8 = 2048 blocks
    dim3 block(16, LROWS, 1);                 // 320 threads = 5 waves
    hipLaunchKernelGGL(peak3d_kernel, grid, block, 0, stream, in, out);
}

// Round 16
// 123.141 us; speedup vs baseline: 1.4750x; 1.1758x over previous
//
#include <hip/hip_runtime.h>

// PostProcessor3D: threshold(>0.9) + 5x5x5 stride-1 maxpool + strict-local-max
// mask on [64,512,512] fp32.
//
// R16: no launch-bounds cap (R14/R15 proved "(320,8)" makes the allocator
// give up: VGPR=32 + scratch spill, WRITE +15MB). Instead shrink live state
// so the allocator lands <=64 naturally:
//   - neighbor loads narrowed to float2: wmax5 needs only left.z/.w and
//     right.x/.y -> load 8B at offm-2 and offm+4 (8B-aligned) instead of two
//     full quads. Prefetch 12 -> 8 quad-regs; staging bytes 48 -> 32/thread.
//   - center re-load from global (no cen LDS/ring), issued pre-barrier ->
//     latency hidden; L2-mostly (staged 2 slices earlier).
// Kept (proven): 320-thread blocks (20 rows x 16 cols, 1 wm quad/thread),
// producer-side register W-max, raw-max trick (out = (c>0.9 && c==rawmax)?
// c:0; zero-pad == -inf pad), one no-drain barrier/slice (lgkmcnt only;
// global loads fly across), dist-1 slice prefetch, fully-unrolled loop
// (constant ring indices -> no dynamic-index scratch, R3 lesson).
//
// Hazards (1 barrier + dbuf wm): write@stage(t) -> B(t) -> read@consume(t);
// read@consume(t) -> B(t+1) -> rewrite@stage(t+2). OK.
// Tile: W=64 x H=16, DCHUNK=8 -> grid 8x32x8 = 2048 blocks; D-neighbors 256
// ids apart -> same XCD under %8 dispatch -> halo re-reads L2-local.

#define THRESH 0.9f

constexpr int D = 64, H = 512, W = 512;
constexpr int HW = H * W;
constexpr int TW = 64;                    // tile width in floats (16 quads)
constexpr int TH = 16;                    // tile height (output rows)
constexpr int DCHUNK = 8;                 // depth outputs per block
constexpr int HALO = 2;
constexpr int LROWS = TH + 2 * HALO;      // 20 staged rows
constexpr int WM_S = 17;                  // wm row stride (16 quads + pad)
constexpr int NS = DCHUNK + 2 * HALO;     // 12 slices per block

typedef float floatx4 __attribute__((ext_vector_type(4)));
typedef float floatx2 __attribute__((ext_vector_type(2)));

__device__ __forceinline__ void barrier_no_drain() {
    asm volatile("s_waitcnt lgkmcnt(0)\n\ts_barrier" ::: "memory");
}

__device__ __forceinline__ float4 max4(float4 a, float4 b) {
    return make_float4(fmaxf(a.x, b.x), fmaxf(a.y, b.y),
                       fmaxf(a.z, b.z), fmaxf(a.w, b.w));
}

// 5-tap sliding max for quad b. f2,f3 = floats at w-2,w-1 (left float2);
// f8,f9 = floats at w+4,w+5 (right float2). out[j] = max over [w+j-2,w+j+2].
__device__ __forceinline__ float4 wmax5s(floatx2 l, float4 b, floatx2 r) {
    const float f2 = l.x, f3 = l.y, f4 = b.x, f5 = b.y, f6 = b.z, f7 = b.w;
    const float f8 = r.x, f9 = r.y;
    const float m45 = fmaxf(f4, f5);
    const float m56 = fmaxf(f5, f6);
    const float m345 = fmaxf(f3, m45);
    const float m456 = fmaxf(f4, m56);
    const float m567 = fmaxf(m56, f7);
    const float m678 = fmaxf(fmaxf(f6, f7), f8);
    float4 q;
    q.x = fmaxf(fmaxf(f2, f6), m345);
    q.y = fmaxf(fmaxf(f3, f7), m456);
    q.z = fmaxf(fmaxf(f4, f8), m567);
    q.w = fmaxf(fmaxf(f5, f9), m678);
    return q;
}

__global__ __launch_bounds__(320)
void peak3d_kernel(const float* __restrict__ in, float* __restrict__ out) {
    __shared__ float4 wm[2][LROWS * WM_S];    // 2 x 340 quads = 10880 B

    const int tx = threadIdx.x;               // 0..15: quad col
    const int ty = threadIdx.y;               // 0..19: staged row

    const int w0 = blockIdx.x * TW;
    const int h0 = blockIdx.y * TH;
    const int d0 = blockIdx.z * DCHUNK;

    // One staged wm quad per thread: row ty, output-quad col tx.
    const int gh  = h0 + ty - HALO;
    const bool vR = (unsigned)gh < (unsigned)H;
    const int gwm = w0 + 4 * tx;              // own quad (always in [0,512))
    const bool vl = vR && (gwm >= 2);         // left float2 at gwm-2
    const bool vr = vR && (gwm + 4 < W);      // right float2 at gwm+4
    const unsigned rbase = (unsigned)(vR ? gh : 0) * W;
    const unsigned offm = rbase + (unsigned)gwm;
    // center/output offset within a slice (used when ty < TH)
    const unsigned ocen = (unsigned)(h0 + ty) * W + (unsigned)gwm;

    const float4 zero4 = make_float4(0.f, 0.f, 0.f, 0.f);
    const floatx2 zero2 = {0.f, 0.f};
    float4 win[5];
#pragma unroll
    for (int k = 0; k < 5; ++k) win[k] = zero4;
    float4 cen_pf = zero4;

    auto loadStage = [&](int dd, float4& m, floatx2& l, floatx2& r) {
        m = zero4; l = zero2; r = zero2;
        if (dd >= 0 && dd < D) {              // wave-uniform
            const float* sb = in + (size_t)dd * HW;
            if (vR) m = *reinterpret_cast<const float4*>(sb + offm);
            if (vl) l = *reinterpret_cast<const floatx2*>(sb + offm - 2);
            if (vr) r = *reinterpret_cast<const floatx2*>(sb + offm + 4);
        }
    };

    float4 pm; floatx2 pl, pr;
    loadStage(d0 - HALO, pm, pl, pr);         // prime slice 0

#pragma unroll
    for (int t = 0; t < NS; ++t) {            // fully unrolled: t constant
        const int buf = t & 1;

        // ---- stage: register W-max -> wm ----
        wm[buf][ty * WM_S + tx] = wmax5s(pl, pm, pr);

        // center re-load for this iteration's output (issued pre-barrier,
        // consumed post-consume; staged 2 slices ago -> L2 hit).
        if (t >= 4 && ty < TH)                // wave-uniform
            cen_pf = *reinterpret_cast<const float4*>(
                in + (size_t)(d0 + (t - 4)) * HW + ocen);

        // prefetch slice t+1 (in flight across barrier + consume)
        if (t + 1 < NS) loadStage(d0 - HALO + t + 1, pm, pl, pr);

        barrier_no_drain();                   // the only barrier per slice

        // ---- consume (waves 0-3): H-max + D-ring + strict-max + store ----
        if (ty < TH) {                        // wave-uniform
            const float4* wp = &wm[buf][ty * WM_S + tx];
            const float4 hv = max4(max4(max4(wp[0 * WM_S], wp[1 * WM_S]),
                                        max4(wp[3 * WM_S], wp[4 * WM_S])),
                                   wp[2 * WM_S]);
            win[t % 5] = hv;                  // HW-max of slice t

            if (t >= 4) {
                const int dout = d0 + (t - 4);     // window center slice t-2
                const float4 mp = max4(max4(max4(win[0], win[1]),
                                            max4(win[2], win[3])), win[4]);
                const float4 c = cen_pf;
                floatx4 res;
                res.x = (c.x > THRESH && mp.x == c.x) ? c.x : 0.f;
                res.y = (c.y > THRESH && mp.y == c.y) ? c.y : 0.f;
                res.z = (c.z > THRESH && mp.z == c.z) ? c.z : 0.f;
                res.w = (c.w > THRESH && mp.w == c.w) ? c.w : 0.f;
                floatx4* op = reinterpret_cast<floatx4*>(
                    out + (size_t)dout * HW + ocen);
                __builtin_nontemporal_store(res, op);
            }
        }
    }
}

extern "C" void kernel_launch(void* const* d_in, const int* in_sizes, int n_in,
                              void* d_out, int out_size, void* d_ws, size_t ws_size,
                              hipStream_t stream) {
    const float* in = (const float*)d_in[0];
    float* out = (float*)d_out;
    dim3 grid(W / TW, H / TH, D / DCHUNK);    // 8 x 32 x 8 = 2048 blocks
    dim3 block(16, LROWS, 1);                 // 320 threads = 5 waves
    hipLaunchKernelGGL(peak3d_kernel, grid, block, 0, stream, in, out);
}

// Round 17
// 119.380 us; speedup vs baseline: 1.5215x; 1.0315x over previous
//
#include <hip/hip_runtime.h>

// PostProcessor3D: threshold(>0.9) + 5x5x5 stride-1 maxpool + strict-local-max
// mask on [64,512,512] fp32.
//
// R17: fat iterations -- 2 slices per barrier. Cross-round invariant
// (R4/R8/R12/R15/R16): duration == hbm_bytes / ~3.1 TB/s regardless of
// structure, while memset hits 6.2 TB/s. The cap is VMEM issue duty cycle:
// 3-4 loads per wave per dependent chain (stage->barrier->ds_reads->rings->
// store). Fix: double the loads per chain. Each iteration stages TWO slices
// (2 x (b128 + 2 x b64) narrow loads), issues 2 center re-loads, one barrier,
// consumes both slices (2 x 5 ds_reads, 2 ring updates, 2 outputs).
// 96 B/thread in flight per iteration (vs 40), 10 barriers/block (vs 20).
//   - DCHUNK=16 (byte-minimum: R12's FETCH 69 MB vs 89 at DCHUNK=8).
//   - wm: 4 slice-buffers indexed s&3. Rewrite of buffer (s+4)&3 == s&3 is
//     separated from slice-s reads by the iteration-(i+1) barrier. OK.
//   - Emit interleave: consume s=2i -> emit k=2i-4 (ring holds 2i-4..2i),
//     THEN consume s=2i+1 (overwrites slot (2i-4)%5) -> emit k=2i-3. OK.
//   - No launch-bounds waves cap (R14/R15: cap => allocator spills to
//     scratch). Natural VGPR ~55-65.
// Kept: producer-side register W-max from narrow loads (R16), raw-max trick
// (out = (c>0.9 && c==rawmax5^3)?c:0; zero-pad == -inf pad; center re-loaded
// from global, L2-hot), no-drain barrier (lgkmcnt only), fully-unrolled loop
// (constant ring indices; R3 lesson).
// Grid (8,32,4): id = x+8y+256z -> D/H neighbors 256/8 apart == same XCD
// under %8 dispatch -> halo re-reads L2-local.

#define THRESH 0.9f

constexpr int D = 64, H = 512, W = 512;
constexpr int HW = H * W;
constexpr int TW = 64;                    // tile width (16 quads)
constexpr int TH = 16;                    // tile height (output rows)
constexpr int DCHUNK = 16;                // depth outputs per block
constexpr int HALO = 2;
constexpr int LROWS = TH + 2 * HALO;      // 20 staged rows
constexpr int WM_S = 17;                  // wm row stride (16 quads + pad)
constexpr int NS = DCHUNK + 2 * HALO;     // 20 slices per block
constexpr int NPAIR = NS / 2;             // 10 fat iterations

typedef float floatx4 __attribute__((ext_vector_type(4)));
typedef float floatx2 __attribute__((ext_vector_type(2)));

__device__ __forceinline__ void barrier_no_drain() {
    asm volatile("s_waitcnt lgkmcnt(0)\n\ts_barrier" ::: "memory");
}

__device__ __forceinline__ float4 max4(float4 a, float4 b) {
    return make_float4(fmaxf(a.x, b.x), fmaxf(a.y, b.y),
                       fmaxf(a.z, b.z), fmaxf(a.w, b.w));
}

// 5-tap sliding max for quad b; l = floats at w-2,w-1; r = floats at w+4,w+5.
__device__ __forceinline__ float4 wmax5s(floatx2 l, float4 b, floatx2 r) {
    const float f2 = l.x, f3 = l.y, f4 = b.x, f5 = b.y, f6 = b.z, f7 = b.w;
    const float f8 = r.x, f9 = r.y;
    const float m45 = fmaxf(f4, f5);
    const float m56 = fmaxf(f5, f6);
    const float m345 = fmaxf(f3, m45);
    const float m456 = fmaxf(f4, m56);
    const float m567 = fmaxf(m56, f7);
    const float m678 = fmaxf(fmaxf(f6, f7), f8);
    float4 q;
    q.x = fmaxf(fmaxf(f2, f6), m345);
    q.y = fmaxf(fmaxf(f3, f7), m456);
    q.z = fmaxf(fmaxf(f4, f8), m567);
    q.w = fmaxf(fmaxf(f5, f9), m678);
    return q;
}

__global__ __launch_bounds__(320)
void peak3d_kernel(const float* __restrict__ in, float* __restrict__ out) {
    __shared__ float4 wm[4][LROWS * WM_S];    // 4 slice-buffers = 21760 B

    const int tx = threadIdx.x;               // 0..15: quad col
    const int ty = threadIdx.y;               // 0..19: staged row

    const int w0 = blockIdx.x * TW;
    const int h0 = blockIdx.y * TH;
    const int d0 = blockIdx.z * DCHUNK;

    const int gh  = h0 + ty - HALO;
    const bool vR = (unsigned)gh < (unsigned)H;
    const int gwm = w0 + 4 * tx;              // own quad (always in [0,512))
    const bool vl = vR && (gwm >= 2);
    const bool vr = vR && (gwm + 4 < W);
    const unsigned rbase = (unsigned)(vR ? gh : 0) * W;
    const unsigned offm = rbase + (unsigned)gwm;
    const unsigned ocen = (unsigned)(h0 + ty) * W + (unsigned)gwm;

    const float4 zero4 = make_float4(0.f, 0.f, 0.f, 0.f);
    const floatx2 zero2 = {0.f, 0.f};
    float4 win[5];
#pragma unroll
    for (int k = 0; k < 5; ++k) win[k] = zero4;
    float4 cen0 = zero4, cen1 = zero4;

    auto loadStage = [&](int s, float4& m, floatx2& l, floatx2& r) {
        m = zero4; l = zero2; r = zero2;
        const int dd = d0 - HALO + s;
        if (dd >= 0 && dd < D) {              // block-uniform
            const float* sb = in + (size_t)dd * HW;
            if (vR) m = *reinterpret_cast<const float4*>(sb + offm);
            if (vl) l = *reinterpret_cast<const floatx2*>(sb + offm - 2);
            if (vr) r = *reinterpret_cast<const floatx2*>(sb + offm + 4);
        }
    };

    float4 pm0, pm1; floatx2 pl0, pr0, pl1, pr1;
    loadStage(0, pm0, pl0, pr0);              // prime pair (slices 0,1)
    loadStage(1, pm1, pl1, pr1);

#pragma unroll
    for (int i = 0; i < NPAIR; ++i) {         // fully unrolled: i constant
        const int s0 = 2 * i, s1 = 2 * i + 1;

        // ---- stage both slices: register W-max -> wm ----
        wm[s0 & 3][ty * WM_S + tx] = wmax5s(pl0, pm0, pr0);
        wm[s1 & 3][ty * WM_S + tx] = wmax5s(pl1, pm1, pr1);

        // center re-loads for this iteration's outputs (k0=2i-4, k1=2i-3);
        // issued pre-barrier, consumed at phase end (L2-hot: staged earlier).
        if (i >= 2 && ty < TH) {
            cen0 = *reinterpret_cast<const float4*>(
                in + (size_t)(d0 + (2 * i - 4)) * HW + ocen);
            cen1 = *reinterpret_cast<const float4*>(
                in + (size_t)(d0 + (2 * i - 3)) * HW + ocen);
        }

        // prefetch next pair (in flight across barrier + consume)
        if (i + 1 < NPAIR) {
            loadStage(s0 + 2, pm0, pl0, pr0);
            loadStage(s1 + 2, pm1, pl1, pr1);
        }

        barrier_no_drain();                   // ONE barrier per 2 slices

        // ---- consume (waves 0-3): 2x (H-max + ring + emit) ----
        if (ty < TH) {                        // wave-uniform
            // slice s0
            {
                const float4* wp = &wm[s0 & 3][ty * WM_S + tx];
                const float4 hv = max4(max4(max4(wp[0 * WM_S], wp[1 * WM_S]),
                                            max4(wp[3 * WM_S], wp[4 * WM_S])),
                                       wp[2 * WM_S]);
                win[s0 % 5] = hv;             // ring now holds s0-4 .. s0
            }
            if (i >= 2) {                     // emit k0 = 2i-4 (window s0-4..s0)
                const int dout = d0 + (2 * i - 4);
                const float4 mp = max4(max4(max4(win[0], win[1]),
                                            max4(win[2], win[3])), win[4]);
                const float4 c = cen0;
                floatx4 res;
                res.x = (c.x > THRESH && mp.x == c.x) ? c.x : 0.f;
                res.y = (c.y > THRESH && mp.y == c.y) ? c.y : 0.f;
                res.z = (c.z > THRESH && mp.z == c.z) ? c.z : 0.f;
                res.w = (c.w > THRESH && mp.w == c.w) ? c.w : 0.f;
                __builtin_nontemporal_store(res, reinterpret_cast<floatx4*>(
                    out + (size_t)dout * HW + ocen));
            }
            // slice s1
            {
                const float4* wp = &wm[s1 & 3][ty * WM_S + tx];
                const float4 hv = max4(max4(max4(wp[0 * WM_S], wp[1 * WM_S]),
                                            max4(wp[3 * WM_S], wp[4 * WM_S])),
                                       wp[2 * WM_S]);
                win[s1 % 5] = hv;             // ring now holds s1-4 .. s1
            }
            if (i >= 2) {                     // emit k1 = 2i-3 (window s1-4..s1)
                const int dout = d0 + (2 * i - 3);
                const float4 mp = max4(max4(max4(win[0], win[1]),
                                            max4(win[2], win[3])), win[4]);
                const float4 c = cen1;
                floatx4 res;
                res.x = (c.x > THRESH && mp.x == c.x) ? c.x : 0.f;
                res.y = (c.y > THRESH && mp.y == c.y) ? c.y : 0.f;
                res.z = (c.z > THRESH && mp.z == c.z) ? c.z : 0.f;
                res.w = (c.w > THRESH && mp.w == c.w) ? c.w : 0.f;
                __builtin_nontemporal_store(res, reinterpret_cast<floatx4*>(
                    out + (size_t)dout * HW + ocen));
            }
        }
        // Hazards: wm[b] written at slice s is re-written at s+4 (iteration
        // i+2 stage), separated from slice-s consume reads by the iteration
        // i+1 barrier. Ring/center regs are private. OK.
    }
}

extern "C" void kernel_launch(void* const* d_in, const int* in_sizes, int n_in,
                              void* d_out, int out_size, void* d_ws, size_t ws_size,
                              hipStream_t stream) {
    const float* in = (const float*)d_in[0];
    float* out = (float*)d_out;
    dim3 grid(W / TW, H / TH, D / DCHUNK);    // 8 x 32 x 4 = 1024 blocks
    dim3 block(16, LROWS, 1);                 // 320 threads = 5 waves
    hipLaunchKernelGGL(peak3d_kernel, grid, block, 0, stream, in, out);
}